// Round 15
// baseline (1122.337 us; speedup 1.0000x reference)
//
#include <hip/hip_runtime.h>
#include <math.h>

#define NVOX 65536
#define DM 256
#define NH 8
#define HDIM 32
#define DFFN 2048
#define SSZ 128
#define SNUM 512

#define AS1 __attribute__((address_space(1)))
#define AS3 __attribute__((address_space(3)))

typedef __attribute__((ext_vector_type(8))) __bf16 bf16x8;
typedef __attribute__((ext_vector_type(8))) unsigned short u16x8;
typedef __attribute__((ext_vector_type(4))) float f32x4;

__device__ __forceinline__ unsigned short f2bf(float f) {
    unsigned int u = __float_as_uint(f);
    u += 0x7fffu + ((u >> 16) & 1u);
    return (unsigned short)(u >> 16);
}
__device__ __forceinline__ float bf2f(unsigned short u) {
    return __uint_as_float(((unsigned int)u) << 16);
}

#define VMCNT0 asm volatile("s_waitcnt vmcnt(0)" ::: "memory")
#define VMCNT4 asm volatile("s_waitcnt vmcnt(4)" ::: "memory")
#define LGKM0  asm volatile("s_waitcnt lgkmcnt(0)" ::: "memory")

// ============== weight fp32 -> bf16 (all 4 arrays, 1 launch) ==============
__global__ __launch_bounds__(256)
void cvt_all_kernel(const float* __restrict__ a, int na,
                    const float* __restrict__ b, int nb,
                    const float* __restrict__ c, int nc,
                    const float* __restrict__ d, int nd,
                    unsigned short* __restrict__ oa, unsigned short* __restrict__ ob,
                    unsigned short* __restrict__ oc, unsigned short* __restrict__ od) {
    int i = blockIdx.x * 256 + threadIdx.x;
    int stride = gridDim.x * 256;
    int n01 = na + nb, n012 = na + nb + nc, ntot = n012 + nd;
    for (; i < ntot; i += stride) {
        if (i < na) oa[i] = f2bf(a[i]);
        else if (i < n01) ob[i - na] = f2bf(b[i - na]);
        else if (i < n012) oc[i - n01] = f2bf(c[i - n01]);
        else od[i - n012] = f2bf(d[i - n012]);
    }
}

// ============================= gather =============================
__global__ __launch_bounds__(256)
void gather_kernel(const float* __restrict__ src, const float* __restrict__ pos,
                   const int* __restrict__ inds,
                   unsigned short* __restrict__ qk, unsigned short* __restrict__ feat) {
    int j = blockIdx.x * 4 + (threadIdx.x >> 6);
    int lane = threadIdx.x & 63;
    int v = inds[j];
    float4 a = ((const float4*)(src + (size_t)v * DM))[lane];
    float4 p = ((const float4*)(pos + (size_t)v * DM))[lane];
    ushort4 qo, fo;
    qo.x = f2bf(a.x + p.x); qo.y = f2bf(a.y + p.y);
    qo.z = f2bf(a.z + p.z); qo.w = f2bf(a.w + p.w);
    fo.x = f2bf(a.x); fo.y = f2bf(a.y); fo.z = f2bf(a.z); fo.w = f2bf(a.w);
    ((ushort4*)(qk   + (size_t)j * DM))[lane] = qo;
    ((ushort4*)(feat + (size_t)j * DM))[lane] = fo;
}

// ================= fused QKV GEMM (one dispatch) ==================
__global__ __launch_bounds__(512)
void qkv_mfma256(const unsigned short* __restrict__ Aqk, const unsigned short* __restrict__ Af,
                 const unsigned short* __restrict__ Wqkv, const float* __restrict__ bqkv,
                 unsigned short* __restrict__ Cqk, unsigned short* __restrict__ Vout) {
    __shared__ alignas(16) char smem[69632];
    unsigned short* As = (unsigned short*)smem;
    unsigned short* Bs = (unsigned short*)(smem + 32768);
    float* ebuf = (float*)smem;
    const int ES = 264;
    const int K = 256;

    int tid = threadIdx.x;
    int wave = tid >> 6, lane = tid & 63;
    int wm = wave >> 2;
    int wn = wave & 3;

    unsigned lin = blockIdx.x + blockIdx.y * gridDim.x;
    unsigned nwg = gridDim.x * gridDim.y;           // 768, %8==0 -> bijective
    unsigned swz = lin;
    if ((nwg & 7u) == 0u) { unsigned cpx = nwg >> 3; swz = (lin & 7u) * cpx + (lin >> 3); }
    int bx = (int)(swz / gridDim.y);
    int by = (int)(swz % gridDim.y);
    int mBase = bx * 256;

    const unsigned short* A = (by < 2) ? Aqk : Af;
    int wrow0 = (by < 2) ? by * 256 : 512;
    int ncol0 = (by < 2) ? by * 256 : 0;
    int Ncols = (by < 2) ? 512 : 256;
    unsigned short* Co = (by < 2) ? Cqk : Vout;
    const float* bias = bqkv + wrow0;

    int rr = lane & 15;
    int kq = (lane >> 4) * 8;
    int rbase = (lane >> 4) * 4;

    f32x4 acc[8][4];
    const f32x4 zero = {0.f, 0.f, 0.f, 0.f};
#pragma unroll
    for (int m = 0; m < 8; m++)
#pragma unroll
        for (int n = 0; n < 4; n++) acc[m][n] = zero;

    const unsigned short* gA0 = A + (size_t)(mBase + (wave * 2 + 0) * 16 + rr) * K + kq;
    const unsigned short* gA1 = A + (size_t)(mBase + (wave * 2 + 1) * 16 + rr) * K + kq;
    const unsigned short* gB0 = Wqkv + (size_t)(wrow0 + (wave * 2 + 0) * 16 + rr) * K + kq;
    const unsigned short* gB1 = Wqkv + (size_t)(wrow0 + (wave * 2 + 1) * 16 + rr) * K + kq;

    auto stage = [&](int b, int kt) {
        int ko = kt * 32;
        __builtin_amdgcn_global_load_lds((const AS1 void*)(gA0 + ko),
            (AS3 void*)(As + b * 8192 + (wave * 2 + 0) * 512), 16, 0, 0);
        __builtin_amdgcn_global_load_lds((const AS1 void*)(gA1 + ko),
            (AS3 void*)(As + b * 8192 + (wave * 2 + 1) * 512), 16, 0, 0);
        __builtin_amdgcn_global_load_lds((const AS1 void*)(gB0 + ko),
            (AS3 void*)(Bs + b * 8192 + (wave * 2 + 0) * 512), 16, 0, 0);
        __builtin_amdgcn_global_load_lds((const AS1 void*)(gB1 + ko),
            (AS3 void*)(Bs + b * 8192 + (wave * 2 + 1) * 512), 16, 0, 0);
    };

    stage(0, 0);
    for (int t = 0; t < 8; ++t) {
        int p = t & 1;
        if (t + 1 < 8) { stage(p ^ 1, t + 1); VMCNT4; }
        else { VMCNT0; }
        __builtin_amdgcn_s_barrier();
        __builtin_amdgcn_sched_barrier(0);

        bf16x8 af[8], bf[4];
#pragma unroll
        for (int m = 0; m < 8; m++)
            af[m] = *(const bf16x8*)(As + p * 8192 + (wm * 8 + m) * 512 + lane * 8);
#pragma unroll
        for (int n = 0; n < 4; n++)
            bf[n] = *(const bf16x8*)(Bs + p * 8192 + (wn * 4 + n) * 512 + lane * 8);
#pragma unroll
        for (int m = 0; m < 8; m++)
#pragma unroll
            for (int n = 0; n < 4; n++)
                acc[m][n] = __builtin_amdgcn_mfma_f32_16x16x32_bf16(af[m], bf[n], acc[m][n], 0, 0, 0);

        __builtin_amdgcn_sched_barrier(0);
        __builtin_amdgcn_s_barrier();
    }

    float bn[4];
#pragma unroll
    for (int n = 0; n < 4; n++)
        bn[n] = bias[wn * 64 + n * 16 + rr];

    int erow = tid >> 3;
    int ec0  = (tid & 7) * 32;
#pragma unroll
    for (int pass = 0; pass < 4; ++pass) {
        __syncthreads();
        if (wm == (pass >> 1)) {
#pragma unroll
            for (int mm = 0; mm < 4; ++mm) {
                int m = (pass & 1) * 4 + mm;
#pragma unroll
                for (int n = 0; n < 4; ++n) {
                    int lcol = wn * 64 + n * 16 + rr;
#pragma unroll
                    for (int r = 0; r < 4; ++r)
                        ebuf[(mm * 16 + rbase + r) * ES + lcol] = acc[m][n][r] + bn[n];
                }
            }
        }
        __syncthreads();
        int grow = mBase + pass * 64 + erow;
        unsigned short* dst = Co + (size_t)grow * Ncols + ncol0 + ec0;
#pragma unroll
        for (int g = 0; g < 4; ++g) {
            u16x8 o;
#pragma unroll
            for (int j = 0; j < 8; ++j)
                o[j] = f2bf(ebuf[erow * ES + ec0 + g * 8 + j]);
            *(u16x8*)(dst + g * 8) = o;
        }
    }
}

// ==================== Wo GEMM + fused LN1 scatter ==================
__global__ __launch_bounds__(512)
void wo_mfma256(const unsigned short* __restrict__ A, const unsigned short* __restrict__ W,
                const float* __restrict__ bias,
                const int* __restrict__ inds, const float* __restrict__ res1,
                const float* __restrict__ g1, const float* __restrict__ b1,
                unsigned short* __restrict__ out2) {
    __shared__ alignas(16) char smem[69632];
    unsigned short* As = (unsigned short*)smem;
    unsigned short* Bs = (unsigned short*)(smem + 32768);
    float* ebuf = (float*)smem;
    const int ES = 264;
    const int K = 256;

    int tid = threadIdx.x;
    int wave = tid >> 6, lane = tid & 63;
    int wm = wave >> 2;
    int wn = wave & 3;

    unsigned lin = blockIdx.x;
    unsigned nwg = gridDim.x;
    unsigned swz = lin;
    if ((nwg & 7u) == 0u) { unsigned cpx = nwg >> 3; swz = (lin & 7u) * cpx + (lin >> 3); }
    int mBase = (int)swz * 256;

    int rr = lane & 15;
    int kq = (lane >> 4) * 8;
    int rbase = (lane >> 4) * 4;

    f32x4 acc[8][4];
    const f32x4 zero = {0.f, 0.f, 0.f, 0.f};
#pragma unroll
    for (int m = 0; m < 8; m++)
#pragma unroll
        for (int n = 0; n < 4; n++) acc[m][n] = zero;

    const unsigned short* gA0 = A + (size_t)(mBase + (wave * 2 + 0) * 16 + rr) * K + kq;
    const unsigned short* gA1 = A + (size_t)(mBase + (wave * 2 + 1) * 16 + rr) * K + kq;
    const unsigned short* gB0 = W + (size_t)((wave * 2 + 0) * 16 + rr) * K + kq;
    const unsigned short* gB1 = W + (size_t)((wave * 2 + 1) * 16 + rr) * K + kq;

    auto stage = [&](int b, int kt) {
        int ko = kt * 32;
        __builtin_amdgcn_global_load_lds((const AS1 void*)(gA0 + ko),
            (AS3 void*)(As + b * 8192 + (wave * 2 + 0) * 512), 16, 0, 0);
        __builtin_amdgcn_global_load_lds((const AS1 void*)(gA1 + ko),
            (AS3 void*)(As + b * 8192 + (wave * 2 + 1) * 512), 16, 0, 0);
        __builtin_amdgcn_global_load_lds((const AS1 void*)(gB0 + ko),
            (AS3 void*)(Bs + b * 8192 + (wave * 2 + 0) * 512), 16, 0, 0);
        __builtin_amdgcn_global_load_lds((const AS1 void*)(gB1 + ko),
            (AS3 void*)(Bs + b * 8192 + (wave * 2 + 1) * 512), 16, 0, 0);
    };

    stage(0, 0);
    for (int t = 0; t < 8; ++t) {
        int p = t & 1;
        if (t + 1 < 8) { stage(p ^ 1, t + 1); VMCNT4; }
        else { VMCNT0; }
        __builtin_amdgcn_s_barrier();
        __builtin_amdgcn_sched_barrier(0);

        bf16x8 af[8], bf[4];
#pragma unroll
        for (int m = 0; m < 8; m++)
            af[m] = *(const bf16x8*)(As + p * 8192 + (wm * 8 + m) * 512 + lane * 8);
#pragma unroll
        for (int n = 0; n < 4; n++)
            bf[n] = *(const bf16x8*)(Bs + p * 8192 + (wn * 4 + n) * 512 + lane * 8);
#pragma unroll
        for (int m = 0; m < 8; m++)
#pragma unroll
            for (int n = 0; n < 4; n++)
                acc[m][n] = __builtin_amdgcn_mfma_f32_16x16x32_bf16(af[m], bf[n], acc[m][n], 0, 0, 0);

        __builtin_amdgcn_sched_barrier(0);
        __builtin_amdgcn_s_barrier();
    }

    float bn[4];
#pragma unroll
    for (int n = 0; n < 4; n++)
        bn[n] = bias[wn * 64 + n * 16 + rr];

    int erow = tid >> 3;
    int ec0  = (tid & 7) * 32;
#pragma unroll
    for (int pass = 0; pass < 4; ++pass) {
        __syncthreads();
        if (wm == (pass >> 1)) {
#pragma unroll
            for (int mm = 0; mm < 4; ++mm) {
                int m = (pass & 1) * 4 + mm;
#pragma unroll
                for (int n = 0; n < 4; ++n) {
                    int lcol = wn * 64 + n * 16 + rr;
#pragma unroll
                    for (int r = 0; r < 4; ++r)
                        ebuf[(mm * 16 + rbase + r) * ES + lcol] = acc[m][n][r] + bn[n];
                }
            }
        }
        __syncthreads();
        int grow = mBase + pass * 64 + erow;
        int v = inds[grow];
        const float* pr = res1 + (size_t)v * 256;
        f32x4 tv[8];
        float s = 0.f, s2 = 0.f;
#pragma unroll
        for (int g = 0; g < 8; ++g) {
            float4 e = *(float4*)(ebuf + erow * ES + ec0 + g * 4);
            float4 p = *(const float4*)(pr + ec0 + g * 4);
            f32x4 t = {e.x + p.x, e.y + p.y, e.z + p.z, e.w + p.w};
            tv[g] = t;
            s += t[0] + t[1] + t[2] + t[3];
            s2 += t[0]*t[0] + t[1]*t[1] + t[2]*t[2] + t[3]*t[3];
        }
#pragma unroll
        for (int off = 1; off < 8; off <<= 1) { s += __shfl_xor(s, off); s2 += __shfl_xor(s2, off); }
        float mean = s * (1.f/256.f);
        float var = fmaf(-mean, mean, s2 * (1.f/256.f));
        float rs = rsqrtf(var + 1e-5f);
        unsigned short* xb = out2 + (size_t)v * 256 + ec0;
#pragma unroll
        for (int g = 0; g < 4; ++g) {
            u16x8 o;
#pragma unroll
            for (int j = 0; j < 8; ++j) {
                int idx = g * 8 + j;
                float gg = g1[ec0 + idx];
                float bb = b1[ec0 + idx];
                o[j] = f2bf(fmaf((tv[idx >> 2][idx & 3] - mean) * rs, gg, bb));
            }
            *(u16x8*)(xb + g * 8) = o;
        }
    }
}

// ===================== fused FFN (FF1+FF2+LN2+LN3) =================
// v5: W in wave-private REGISTERS, unroll-by-2 with named sets wA/wB,
// loads issued AFTER their consumer MFMA (issue-after-consume -> depth
// ~1 MFMA-block vs ~200cy L2 latency). ZERO inner barriers; only the Hs
// transpose exchange (2 barriers/chunk). LDS: Xs 64KB + Hs 64KB = 128KB.
__global__ __launch_bounds__(512, 1)
void ffn_fused(const unsigned short* __restrict__ X,   // [NVOX][256] bf16 (x_bf)
               const unsigned short* __restrict__ W1,  // [2048][256] bf16
               const unsigned short* __restrict__ W2,  // [256][2048] bf16
               const float* __restrict__ b1g,          // [2048]
               const float* __restrict__ b2g,          // [256]
               const float* __restrict__ prev,         // [NVOX][256] f32
               const float* __restrict__ lnG1, const float* __restrict__ lnB1,
               const float* __restrict__ lnG2, const float* __restrict__ lnB2,
               float* __restrict__ out) {
    __shared__ alignas(16) char smem[131072];
    unsigned short* Xs = (unsigned short*)smem;        // 64 subtiles x 512 u16
    char*           HsB = smem + 65536;                // 128x256 u16 (swizzled)
    float*          ebuf = (float*)smem;               // epilogue alias (16x264)
    const int ES = 264;

    int tid = threadIdx.x;
    int wave = tid >> 6, lane = tid & 63;
    int wm = wave >> 2;          // 0..1: rows wm*64..+64
    int wn = wave & 3;           // 0..3: cols wn*64..+64
    int mBase = blockIdx.x * 128;
    int rr = lane & 15;
    int kq = (lane >> 4) * 8;
    int rbase = (lane >> 4) * 4;

    // ---- prologue: stage ALL of X in fragment order ----
#pragma unroll
    for (int u = 0; u < 8; ++u)
        __builtin_amdgcn_global_load_lds(
            (const AS1 void*)(X + (size_t)(mBase + wave * 16 + rr) * 256 + u * 32 + kq),
            (AS3 void*)(Xs + (wave * 8 + u) * 512), 16, 0, 0);

    // wave-private W fragment loads (global -> VGPR; L2-resident).
    // slice s (0..127): c=s>>4, half=(s>>3)&1, kt=s&7.
    auto loadW = [&](int s, bf16x8* dst) {
        int c = s >> 4, half = (s >> 3) & 1, kt = s & 7;
        if (half == 0) {
#pragma unroll
            for (int n = 0; n < 4; n++)
                dst[n] = *(const bf16x8*)(W1 + (size_t)(c * 256 + wn * 64 + n * 16 + rr) * 256 + kt * 32 + kq);
        } else {
#pragma unroll
            for (int n = 0; n < 4; n++)
                dst[n] = *(const bf16x8*)(W2 + (size_t)(wn * 64 + n * 16 + rr) * 2048 + c * 256 + kt * 32 + kq);
        }
    };

    f32x4 yacc[4][4];
    const f32x4 zero = {0.f, 0.f, 0.f, 0.f};
#pragma unroll
    for (int m = 0; m < 4; m++)
#pragma unroll
        for (int n = 0; n < 4; n++) yacc[m][n] = zero;

    bf16x8 wA[4], wB[4];
    loadW(0, wA);
    loadW(1, wB);
    __syncthreads();   // X staged; prologue W loads also complete

    for (int c = 0; c < 8; ++c) {
        int s0 = c * 16;
        f32x4 hacc[4][4];
#pragma unroll
        for (int m = 0; m < 4; m++)
#pragma unroll
            for (int n = 0; n < 4; n++) hacc[m][n] = zero;

        // ---- FF1: 8 slices, barrier-free, unroll-by-2 (wA/wB) ----
#pragma unroll
        for (int kt = 0; kt < 8; kt += 2) {
            bf16x8 af[4];
#pragma unroll
            for (int m = 0; m < 4; m++)
                af[m] = *(const bf16x8*)(Xs + ((wm * 4 + m) * 8 + kt) * 512 + lane * 8);
#pragma unroll
            for (int m = 0; m < 4; m++)
#pragma unroll
                for (int n = 0; n < 4; n++)
                    hacc[m][n] = __builtin_amdgcn_mfma_f32_16x16x32_bf16(af[m], wA[n], hacc[m][n], 0, 0, 0);
            loadW(s0 + kt + 2, wA);      // issue AFTER consume (stays in flight)

#pragma unroll
            for (int m = 0; m < 4; m++)
                af[m] = *(const bf16x8*)(Xs + ((wm * 4 + m) * 8 + kt + 1) * 512 + lane * 8);
#pragma unroll
            for (int m = 0; m < 4; m++)
#pragma unroll
                for (int n = 0; n < 4; n++)
                    hacc[m][n] = __builtin_amdgcn_mfma_f32_16x16x32_bf16(af[m], wB[n], hacc[m][n], 0, 0, 0);
            loadW(s0 + kt + 3, wB);
        }
        // here wA = slice s0+8 (FF2 kt0), wB = s0+9 — in flight across exchange

        // ---- Hs transpose exchange (the only cross-wave dependency) ----
        __builtin_amdgcn_s_barrier();    // all waves done reading Hs (prev FF2)
        {
            float b1v[4];
#pragma unroll
            for (int n = 0; n < 4; n++)
                b1v[n] = b1g[c * 256 + wn * 64 + n * 16 + rr];
#pragma unroll
            for (int m = 0; m < 4; m++)
#pragma unroll
                for (int n = 0; n < 4; n++)
#pragma unroll
                    for (int r = 0; r < 4; r++) {
                        float v = fmaxf(hacc[m][n][r] + b1v[n], 0.f);
                        int row = wm * 64 + m * 16 + rbase + r;
                        int col = wn * 64 + n * 16 + rr;
                        unsigned byte = (unsigned)(row * 512 + col * 2) ^ ((row & 7) << 4);
                        *(unsigned short*)(HsB + byte) = f2bf(v);
                    }
            LGKM0;
            __builtin_amdgcn_s_barrier();  // Hs writes visible
        }

        // ---- FF2: 8 slices, barrier-free, unroll-by-2 ----
#pragma unroll
        for (int kt = 0; kt < 8; kt += 2) {
            bf16x8 af[4];
#pragma unroll
            for (int m = 0; m < 4; m++) {
                int row = wm * 64 + m * 16 + rr;
                unsigned byte = (unsigned)(row * 512 + kt * 64 + (lane >> 4) * 16) ^ ((rr & 7) << 4);
                af[m] = *(const bf16x8*)(HsB + byte);
            }
#pragma unroll
            for (int m = 0; m < 4; m++)
#pragma unroll
                for (int n = 0; n < 4; n++)
                    yacc[m][n] = __builtin_amdgcn_mfma_f32_16x16x32_bf16(af[m], wA[n], yacc[m][n], 0, 0, 0);
            if (s0 + kt + 10 < 128) loadW(s0 + kt + 10, wA);

#pragma unroll
            for (int m = 0; m < 4; m++) {
                int row = wm * 64 + m * 16 + rr;
                unsigned byte = (unsigned)(row * 512 + (kt + 1) * 64 + (lane >> 4) * 16) ^ ((rr & 7) << 4);
                af[m] = *(const bf16x8*)(HsB + byte);
            }
#pragma unroll
            for (int m = 0; m < 4; m++)
#pragma unroll
                for (int n = 0; n < 4; n++)
                    yacc[m][n] = __builtin_amdgcn_mfma_f32_16x16x32_bf16(af[m], wB[n], yacc[m][n], 0, 0, 0);
            if (s0 + kt + 11 < 128) loadW(s0 + kt + 11, wB);
        }
    }

    // ---- epilogue: out = LN( LN(y + b2 + x_bf) + prev ), 8 passes x 16 rows ----
    float b2v[4];
#pragma unroll
    for (int n = 0; n < 4; n++)
        b2v[n] = b2g[wn * 64 + n * 16 + rr];

    int erow = tid >> 5;              // 0..15
    int ec0  = (tid & 31) * 8;        // 0..248
#pragma unroll
    for (int p = 0; p < 8; ++p) {
        __syncthreads();
        if (wm == (p >> 2)) {
            const int m = p & 3;
#pragma unroll
            for (int n = 0; n < 4; ++n) {
                int lcol = wn * 64 + n * 16 + rr;
#pragma unroll
                for (int r = 0; r < 4; ++r)
                    ebuf[(rbase + r) * ES + lcol] = yacc[m][n][r] + b2v[n];
            }
        }
        __syncthreads();
        int grow = mBase + p * 16 + erow;

        float tv[8];
        float s1 = 0.f, s2 = 0.f;
        const unsigned short* xr = X + (size_t)grow * 256 + ec0;
        u16x8 xv = *(const u16x8*)xr;
#pragma unroll
        for (int j = 0; j < 8; ++j) {
            float t = ebuf[erow * ES + ec0 + j] + bf2f(xv[j]);
            tv[j] = t; s1 += t; s2 += t * t;
        }
#pragma unroll
        for (int off = 1; off < 32; off <<= 1) { s1 += __shfl_xor(s1, off); s2 += __shfl_xor(s2, off); }
        float mean = s1 * (1.f/256.f);
        float var = fmaf(-mean, mean, s2 * (1.f/256.f));
        float rs = rsqrtf(var + 1e-5f);

        const float* pr = prev + (size_t)grow * 256 + ec0;
        float s3 = 0.f, s4 = 0.f;
#pragma unroll
        for (int j = 0; j < 8; ++j) {
            float u = fmaf((tv[j] - mean) * rs, lnG1[ec0 + j], lnB1[ec0 + j]) + pr[j];
            tv[j] = u; s3 += u; s4 += u * u;
        }
#pragma unroll
        for (int off = 1; off < 32; off <<= 1) { s3 += __shfl_xor(s3, off); s4 += __shfl_xor(s4, off); }
        float mean2 = s3 * (1.f/256.f);
        float var2 = fmaf(-mean2, mean2, s4 * (1.f/256.f));
        float rs2 = rsqrtf(var2 + 1e-5f);

        float* od = out + (size_t)grow * 256 + ec0;
#pragma unroll
        for (int g = 0; g < 2; ++g) {
            float4 o;
            o.x = fmaf((tv[g*4+0] - mean2) * rs2, lnG2[ec0 + g*4+0], lnB2[ec0 + g*4+0]);
            o.y = fmaf((tv[g*4+1] - mean2) * rs2, lnG2[ec0 + g*4+1], lnB2[ec0 + g*4+1]);
            o.z = fmaf((tv[g*4+2] - mean2) * rs2, lnG2[ec0 + g*4+2], lnB2[ec0 + g*4+2]);
            o.w = fmaf((tv[g*4+3] - mean2) * rs2, lnG2[ec0 + g*4+3], lnB2[ec0 + g*4+3]);
            *(float4*)(od + g * 4) = o;
        }
    }
}

// ======================= MFMA attention ===========================
__global__ __launch_bounds__(256)
void attn_mfma_kernel(const unsigned short* __restrict__ QK,
                      const unsigned short* __restrict__ V,
                      const unsigned char* __restrict__ mask,
                      unsigned short* __restrict__ ao) {
    int s = blockIdx.x, h = blockIdx.y;
    int tid = threadIdx.x;
    int wq = tid >> 6;
    int lane = tid & 63;

    __shared__ alignas(16) unsigned short Ks[128 * 40];
    __shared__ alignas(16) unsigned short Vt[32 * 136];
    __shared__ alignas(16) unsigned short Plds[4 * 4096];
    __shared__ unsigned char msk[SSZ];

#pragma unroll
    for (int it = 0; it < 2; it++) {
        int idx = tid + it * 256;
        int key = idx >> 2, dimoff = (idx & 3) * 8;
        bf16x8 kv = *(const bf16x8*)(QK + (size_t)(s * SSZ + key) * 512 + 256 + h * HDIM + dimoff);
        *(bf16x8*)(Ks + key * 40 + dimoff) = kv;
        u16x8 vv = *(const u16x8*)(V + (size_t)(s * SSZ + key) * DM + h * HDIM + dimoff);
#pragma unroll
        for (int j = 0; j < 8; j++) Vt[(dimoff + j) * 136 + key] = vv[j];
    }
    if (tid < SSZ) msk[tid] = mask[s * SSZ + tid];
    __syncthreads();

    int rr = lane & 15;
    int kq = (lane >> 4) * 8;
    const f32x4 zero = {0.f, 0.f, 0.f, 0.f};

    bf16x8 qa[2];
#pragma unroll
    for (int mt = 0; mt < 2; mt++)
        qa[mt] = *(const bf16x8*)(QK + (size_t)(s * SSZ + wq * 32 + mt * 16 + rr) * 512 + h * HDIM + kq);

    f32x4 S[2][8];
    __builtin_amdgcn_s_setprio(1);
#pragma unroll
    for (int nt = 0; nt < 8; nt++) {
        bf16x8 kb = *(const bf16x8*)(Ks + (nt * 16 + rr) * 40 + kq);
#pragma unroll
        for (int mt = 0; mt < 2; mt++)
            S[mt][nt] = __builtin_amdgcn_mfma_f32_16x16x32_bf16(qa[mt], kb, zero, 0, 0, 0);
    }
    __builtin_amdgcn_s_setprio(0);

    const float SCALE = 0.17677669529663687f;
    f32x4 rm[2];
#pragma unroll
    for (int mt = 0; mt < 2; mt++) { rm[mt].x = rm[mt].y = rm[mt].z = rm[mt].w = -1e30f; }
#pragma unroll
    for (int nt = 0; nt < 8; nt++) {
        bool mv = msk[nt * 16 + rr] != 0;
#pragma unroll
        for (int mt = 0; mt < 2; mt++) {
#pragma unroll
            for (int r = 0; r < 4; r++) {
                float v = mv ? -1e30f : S[mt][nt][r] * SCALE;
                S[mt][nt][r] = v;
                rm[mt][r] = fmaxf(rm[mt][r], v);
            }
        }
    }
#pragma unroll
    for (int off = 1; off < 16; off <<= 1) {
#pragma unroll
        for (int mt = 0; mt < 2; mt++)
#pragma unroll
            for (int r = 0; r < 4; r++)
                rm[mt][r] = fmaxf(rm[mt][r], __shfl_xor(rm[mt][r], off));
    }

    f32x4 rs[2];
#pragma unroll
    for (int mt = 0; mt < 2; mt++) { rs[mt] = zero; }
#pragma unroll
    for (int nt = 0; nt < 8; nt++)
#pragma unroll
        for (int mt = 0; mt < 2; mt++)
#pragma unroll
            for (int r = 0; r < 4; r++) {
                float p = __expf(S[mt][nt][r] - rm[mt][r]);
                S[mt][nt][r] = p;
                rs[mt][r] += p;
            }
#pragma unroll
    for (int off = 1; off < 16; off <<= 1) {
#pragma unroll
        for (int mt = 0; mt < 2; mt++)
#pragma unroll
            for (int r = 0; r < 4; r++)
                rs[mt][r] += __shfl_xor(rs[mt][r], off);
    }

    char* Pbase = (char*)Plds + wq * 8192;
#pragma unroll
    for (int nt = 0; nt < 8; nt++)
#pragma unroll
        for (int mt = 0; mt < 2; mt++)
#pragma unroll
            for (int r = 0; r < 4; r++) {
                int prow = mt * 16 + (lane >> 4) * 4 + r;
                int col  = nt * 16 + rr;
                unsigned addr = (unsigned)(prow * 256 + col * 2) ^ ((prow & 7) << 4);
                *(unsigned short*)(Pbase + addr) = f2bf(S[mt][nt][r]);
            }
    __syncthreads();

    f32x4 O[2][2];
#pragma unroll
    for (int mt = 0; mt < 2; mt++)
#pragma unroll
        for (int nd = 0; nd < 2; nd++) O[mt][nd] = zero;
    __builtin_amdgcn_s_setprio(1);
#pragma unroll
    for (int kc = 0; kc < 4; kc++) {
        bf16x8 pa[2];
#pragma unroll
        for (int mt = 0; mt < 2; mt++) {
            int prow = mt * 16 + rr;
            unsigned addr = (unsigned)(prow * 256 + (kc * 32 + kq) * 2) ^ ((prow & 7) << 4);
            pa[mt] = *(const bf16x8*)(Pbase + addr);
        }
#pragma unroll
        for (int nd = 0; nd < 2; nd++) {
            bf16x8 vb = *(const bf16x8*)(Vt + (nd * 16 + rr) * 136 + kc * 32 + kq);
#pragma unroll
            for (int mt = 0; mt < 2; mt++)
                O[mt][nd] = __builtin_amdgcn_mfma_f32_16x16x32_bf16(pa[mt], vb, O[mt][nd], 0, 0, 0);
        }
    }
    __builtin_amdgcn_s_setprio(0);

#pragma unroll
    for (int mt = 0; mt < 2; mt++) {
#pragma unroll
        for (int nd = 0; nd < 2; nd++) {
#pragma unroll
            for (int r = 0; r < 4; r++) {
                int row = s * SSZ + wq * 32 + mt * 16 + (lane >> 4) * 4 + r;
                int col = h * HDIM + nd * 16 + rr;
                ao[(size_t)row * DM + col] = f2bf(O[mt][nd][r] / rs[mt][r]);
            }
        }
    }
}

// ============================= launch =============================
extern "C" void kernel_launch(void* const* d_in, const int* in_sizes, int n_in,
                              void* d_out, int out_size, void* d_ws, size_t ws_size,
                              hipStream_t stream) {
    const float* src       = (const float*)d_in[0];
    const float* pos_embed = (const float*)d_in[1];
    const int*   inds_all  = (const int*)d_in[2];
    const unsigned char* masks_all = (const unsigned char*)d_in[3];
    const float* w_qkv = (const float*)d_in[4];
    const float* b_qkv = (const float*)d_in[5];
    const float* w_out = (const float*)d_in[6];
    const float* b_out = (const float*)d_in[7];
    const float* w_ff1 = (const float*)d_in[8];
    const float* b_ff1 = (const float*)d_in[9];
    const float* w_ff2 = (const float*)d_in[10];
    const float* b_ff2 = (const float*)d_in[11];
    const float* g_n1 = (const float*)d_in[12];
    const float* b_n1 = (const float*)d_in[13];
    const float* g_n2 = (const float*)d_in[14];
    const float* b_n2 = (const float*)d_in[15];
    const float* g_ln = (const float*)d_in[16];
    const float* b_ln = (const float*)d_in[17];
    float* out = (float*)d_out;

    const size_t NVF = (size_t)NVOX * DM;  // 16,777,216
    unsigned short* A = (unsigned short*)d_ws;   // NVF u16: qk_bf -> ao_bf
    unsigned short* B = A + NVF;                 // NVF u16: feat_bf -> x_bf
    unsigned short* C = B + NVF;                 // 2*NVF u16: [Q|K]
    unsigned short* D = C + 2 * NVF;             // NVF u16: V bf16
    unsigned short* wts = D + NVF;
    const size_t SZ_QKV = (size_t)2 * 3 * DM * DM;
    const size_t SZ_WO  = (size_t)2 * DM * DM;
    const size_t SZ_FF1 = (size_t)2 * DFFN * DM;
    const size_t SZ_FF2 = (size_t)2 * DM * DFFN;
    unsigned short* wqkv_bf = wts;
    unsigned short* wo_bf   = wqkv_bf + SZ_QKV;
    unsigned short* wff1_bf = wo_bf + SZ_WO;
    unsigned short* wff2_bf = wff1_bf + SZ_FF1;

    cvt_all_kernel<<<1024, 256, 0, stream>>>(
        w_qkv, (int)SZ_QKV, w_out, (int)SZ_WO, w_ff1, (int)SZ_FF1, w_ff2, (int)SZ_FF2,
        wqkv_bf, wo_bf, wff1_bf, wff2_bf);

    for (int i = 0; i < 2; i++) {
        const float* prev = (i == 0) ? src : out;
        const int* inds = inds_all + (size_t)i * 2 * SNUM * SSZ;
        const unsigned char* mask = masks_all + (size_t)i * 2 * SNUM * SSZ;
        const float* pos  = pos_embed + (size_t)i * NVF;
        const unsigned short* wqkv = wqkv_bf + (size_t)i * 3 * DM * DM;
        const unsigned short* wo   = wo_bf + (size_t)i * DM * DM;
        const unsigned short* wff1 = wff1_bf + (size_t)i * DFFN * DM;
        const unsigned short* wff2 = wff2_bf + (size_t)i * DM * DFFN;
        const float* bqkv = b_qkv + (size_t)i * 3 * DM;
        const float* bo   = b_out + (size_t)i * DM;
        const float* bff1 = b_ff1 + (size_t)i * DFFN;
        const float* bff2 = b_ff2 + (size_t)i * DM;

        gather_kernel<<<NVOX / 4, 256, 0, stream>>>(prev, pos, inds, A, B);

        // [Q|K] -> C and V -> D in ONE dispatch (grid 256x3)
        qkv_mfma256<<<dim3(NVOX / 256, 3), 512, 0, stream>>>(
            A, B, wqkv, bqkv, C, D);

        attn_mfma_kernel<<<dim3(SNUM, NH), 256, 0, stream>>>(C, D, mask, A);

        // Wo GEMM + fused LN1 scatter: x[v]=LN(a+prev[v]) -> B (bf16 only)
        wo_mfma256<<<dim3(NVOX / 256), 512, 0, stream>>>(
            A, wo, bo, inds, prev, g_n1 + i * DM, b_n1 + i * DM, B);

        // fused FFN + LN2 + LN3 -> out (barrier-free W reg pipeline)
        ffn_fused<<<dim3(NVOX / 128), 512, 0, stream>>>(
            B, wff1, wff2, bff1, bff2, prev,
            g_n2 + i * DM, b_n2 + i * DM, g_ln + i * DM, b_ln + i * DM, out);
    }
}

// Round 16
// 947.567 us; speedup vs baseline: 1.1844x; 1.1844x over previous
//
#include <hip/hip_runtime.h>
#include <math.h>

#define NVOX 65536
#define DM 256
#define NH 8
#define HDIM 32
#define DFFN 2048
#define SSZ 128
#define SNUM 512

#define AS1 __attribute__((address_space(1)))
#define AS3 __attribute__((address_space(3)))

typedef __attribute__((ext_vector_type(8))) __bf16 bf16x8;
typedef __attribute__((ext_vector_type(8))) unsigned short u16x8;
typedef __attribute__((ext_vector_type(4))) float f32x4;

__device__ __forceinline__ unsigned short f2bf(float f) {
    unsigned int u = __float_as_uint(f);
    u += 0x7fffu + ((u >> 16) & 1u);
    return (unsigned short)(u >> 16);
}
__device__ __forceinline__ float bf2f(unsigned short u) {
    return __uint_as_float(((unsigned int)u) << 16);
}

#define VMCNT0 asm volatile("s_waitcnt vmcnt(0)" ::: "memory")
#define VMCNT2 asm volatile("s_waitcnt vmcnt(2)" ::: "memory")
#define VMCNT4 asm volatile("s_waitcnt vmcnt(4)" ::: "memory")
#define LGKM0  asm volatile("s_waitcnt lgkmcnt(0)" ::: "memory")

// ============== weight fp32 -> bf16 (all 4 arrays, 1 launch) ==============
__global__ __launch_bounds__(256)
void cvt_all_kernel(const float* __restrict__ a, int na,
                    const float* __restrict__ b, int nb,
                    const float* __restrict__ c, int nc,
                    const float* __restrict__ d, int nd,
                    unsigned short* __restrict__ oa, unsigned short* __restrict__ ob,
                    unsigned short* __restrict__ oc, unsigned short* __restrict__ od) {
    int i = blockIdx.x * 256 + threadIdx.x;
    int stride = gridDim.x * 256;
    int n01 = na + nb, n012 = na + nb + nc, ntot = n012 + nd;
    for (; i < ntot; i += stride) {
        if (i < na) oa[i] = f2bf(a[i]);
        else if (i < n01) ob[i - na] = f2bf(b[i - na]);
        else if (i < n012) oc[i - n01] = f2bf(c[i - n01]);
        else od[i - n012] = f2bf(d[i - n012]);
    }
}

// ============================= gather =============================
__global__ __launch_bounds__(256)
void gather_kernel(const float* __restrict__ src, const float* __restrict__ pos,
                   const int* __restrict__ inds,
                   unsigned short* __restrict__ qk, unsigned short* __restrict__ feat) {
    int j = blockIdx.x * 4 + (threadIdx.x >> 6);
    int lane = threadIdx.x & 63;
    int v = inds[j];
    float4 a = ((const float4*)(src + (size_t)v * DM))[lane];
    float4 p = ((const float4*)(pos + (size_t)v * DM))[lane];
    ushort4 qo, fo;
    qo.x = f2bf(a.x + p.x); qo.y = f2bf(a.y + p.y);
    qo.z = f2bf(a.z + p.z); qo.w = f2bf(a.w + p.w);
    fo.x = f2bf(a.x); fo.y = f2bf(a.y); fo.z = f2bf(a.z); fo.w = f2bf(a.w);
    ((ushort4*)(qk   + (size_t)j * DM))[lane] = qo;
    ((ushort4*)(feat + (size_t)j * DM))[lane] = fo;
}

// ================= fused QKV GEMM (one dispatch) ==================
__global__ __launch_bounds__(512)
void qkv_mfma256(const unsigned short* __restrict__ Aqk, const unsigned short* __restrict__ Af,
                 const unsigned short* __restrict__ Wqkv, const float* __restrict__ bqkv,
                 unsigned short* __restrict__ Cqk, unsigned short* __restrict__ Vout) {
    __shared__ alignas(16) char smem[69632];
    unsigned short* As = (unsigned short*)smem;
    unsigned short* Bs = (unsigned short*)(smem + 32768);
    float* ebuf = (float*)smem;
    const int ES = 264;
    const int K = 256;

    int tid = threadIdx.x;
    int wave = tid >> 6, lane = tid & 63;
    int wm = wave >> 2;
    int wn = wave & 3;

    unsigned lin = blockIdx.x + blockIdx.y * gridDim.x;
    unsigned nwg = gridDim.x * gridDim.y;           // 768, %8==0 -> bijective
    unsigned swz = lin;
    if ((nwg & 7u) == 0u) { unsigned cpx = nwg >> 3; swz = (lin & 7u) * cpx + (lin >> 3); }
    int bx = (int)(swz / gridDim.y);
    int by = (int)(swz % gridDim.y);
    int mBase = bx * 256;

    const unsigned short* A = (by < 2) ? Aqk : Af;
    int wrow0 = (by < 2) ? by * 256 : 512;
    int ncol0 = (by < 2) ? by * 256 : 0;
    int Ncols = (by < 2) ? 512 : 256;
    unsigned short* Co = (by < 2) ? Cqk : Vout;
    const float* bias = bqkv + wrow0;

    int rr = lane & 15;
    int kq = (lane >> 4) * 8;
    int rbase = (lane >> 4) * 4;

    f32x4 acc[8][4];
    const f32x4 zero = {0.f, 0.f, 0.f, 0.f};
#pragma unroll
    for (int m = 0; m < 8; m++)
#pragma unroll
        for (int n = 0; n < 4; n++) acc[m][n] = zero;

    const unsigned short* gA0 = A + (size_t)(mBase + (wave * 2 + 0) * 16 + rr) * K + kq;
    const unsigned short* gA1 = A + (size_t)(mBase + (wave * 2 + 1) * 16 + rr) * K + kq;
    const unsigned short* gB0 = Wqkv + (size_t)(wrow0 + (wave * 2 + 0) * 16 + rr) * K + kq;
    const unsigned short* gB1 = Wqkv + (size_t)(wrow0 + (wave * 2 + 1) * 16 + rr) * K + kq;

    auto stage = [&](int b, int kt) {
        int ko = kt * 32;
        __builtin_amdgcn_global_load_lds((const AS1 void*)(gA0 + ko),
            (AS3 void*)(As + b * 8192 + (wave * 2 + 0) * 512), 16, 0, 0);
        __builtin_amdgcn_global_load_lds((const AS1 void*)(gA1 + ko),
            (AS3 void*)(As + b * 8192 + (wave * 2 + 1) * 512), 16, 0, 0);
        __builtin_amdgcn_global_load_lds((const AS1 void*)(gB0 + ko),
            (AS3 void*)(Bs + b * 8192 + (wave * 2 + 0) * 512), 16, 0, 0);
        __builtin_amdgcn_global_load_lds((const AS1 void*)(gB1 + ko),
            (AS3 void*)(Bs + b * 8192 + (wave * 2 + 1) * 512), 16, 0, 0);
    };

    stage(0, 0);
    for (int t = 0; t < 8; ++t) {
        int p = t & 1;
        if (t + 1 < 8) { stage(p ^ 1, t + 1); VMCNT4; }
        else { VMCNT0; }
        __builtin_amdgcn_s_barrier();
        __builtin_amdgcn_sched_barrier(0);

        bf16x8 af[8], bf[4];
#pragma unroll
        for (int m = 0; m < 8; m++)
            af[m] = *(const bf16x8*)(As + p * 8192 + (wm * 8 + m) * 512 + lane * 8);
#pragma unroll
        for (int n = 0; n < 4; n++)
            bf[n] = *(const bf16x8*)(Bs + p * 8192 + (wn * 4 + n) * 512 + lane * 8);
#pragma unroll
        for (int m = 0; m < 8; m++)
#pragma unroll
            for (int n = 0; n < 4; n++)
                acc[m][n] = __builtin_amdgcn_mfma_f32_16x16x32_bf16(af[m], bf[n], acc[m][n], 0, 0, 0);

        __builtin_amdgcn_sched_barrier(0);
        __builtin_amdgcn_s_barrier();
    }

    float bn[4];
#pragma unroll
    for (int n = 0; n < 4; n++)
        bn[n] = bias[wn * 64 + n * 16 + rr];

    int erow = tid >> 3;
    int ec0  = (tid & 7) * 32;
#pragma unroll
    for (int pass = 0; pass < 4; ++pass) {
        __syncthreads();
        if (wm == (pass >> 1)) {
#pragma unroll
            for (int mm = 0; mm < 4; ++mm) {
                int m = (pass & 1) * 4 + mm;
#pragma unroll
                for (int n = 0; n < 4; ++n) {
                    int lcol = wn * 64 + n * 16 + rr;
#pragma unroll
                    for (int r = 0; r < 4; ++r)
                        ebuf[(mm * 16 + rbase + r) * ES + lcol] = acc[m][n][r] + bn[n];
                }
            }
        }
        __syncthreads();
        int grow = mBase + pass * 64 + erow;
        unsigned short* dst = Co + (size_t)grow * Ncols + ncol0 + ec0;
#pragma unroll
        for (int g = 0; g < 4; ++g) {
            u16x8 o;
#pragma unroll
            for (int j = 0; j < 8; ++j)
                o[j] = f2bf(ebuf[erow * ES + ec0 + g * 8 + j]);
            *(u16x8*)(dst + g * 8) = o;
        }
    }
}

// ==================== Wo GEMM + fused LN1 scatter ==================
// x[v] = LN(aW^T + bias + res1[v]); v = inds[row]; bf16 out ONLY.
__global__ __launch_bounds__(512)
void wo_mfma256(const unsigned short* __restrict__ A, const unsigned short* __restrict__ W,
                const float* __restrict__ bias,
                const int* __restrict__ inds, const float* __restrict__ res1,
                const float* __restrict__ g1, const float* __restrict__ b1,
                unsigned short* __restrict__ out2) {
    __shared__ alignas(16) char smem[69632];
    unsigned short* As = (unsigned short*)smem;
    unsigned short* Bs = (unsigned short*)(smem + 32768);
    float* ebuf = (float*)smem;
    const int ES = 264;
    const int K = 256;

    int tid = threadIdx.x;
    int wave = tid >> 6, lane = tid & 63;
    int wm = wave >> 2;
    int wn = wave & 3;

    unsigned lin = blockIdx.x;
    unsigned nwg = gridDim.x;
    unsigned swz = lin;
    if ((nwg & 7u) == 0u) { unsigned cpx = nwg >> 3; swz = (lin & 7u) * cpx + (lin >> 3); }
    int mBase = (int)swz * 256;

    int rr = lane & 15;
    int kq = (lane >> 4) * 8;
    int rbase = (lane >> 4) * 4;

    f32x4 acc[8][4];
    const f32x4 zero = {0.f, 0.f, 0.f, 0.f};
#pragma unroll
    for (int m = 0; m < 8; m++)
#pragma unroll
        for (int n = 0; n < 4; n++) acc[m][n] = zero;

    const unsigned short* gA0 = A + (size_t)(mBase + (wave * 2 + 0) * 16 + rr) * K + kq;
    const unsigned short* gA1 = A + (size_t)(mBase + (wave * 2 + 1) * 16 + rr) * K + kq;
    const unsigned short* gB0 = W + (size_t)((wave * 2 + 0) * 16 + rr) * K + kq;
    const unsigned short* gB1 = W + (size_t)((wave * 2 + 1) * 16 + rr) * K + kq;

    auto stage = [&](int b, int kt) {
        int ko = kt * 32;
        __builtin_amdgcn_global_load_lds((const AS1 void*)(gA0 + ko),
            (AS3 void*)(As + b * 8192 + (wave * 2 + 0) * 512), 16, 0, 0);
        __builtin_amdgcn_global_load_lds((const AS1 void*)(gA1 + ko),
            (AS3 void*)(As + b * 8192 + (wave * 2 + 1) * 512), 16, 0, 0);
        __builtin_amdgcn_global_load_lds((const AS1 void*)(gB0 + ko),
            (AS3 void*)(Bs + b * 8192 + (wave * 2 + 0) * 512), 16, 0, 0);
        __builtin_amdgcn_global_load_lds((const AS1 void*)(gB1 + ko),
            (AS3 void*)(Bs + b * 8192 + (wave * 2 + 1) * 512), 16, 0, 0);
    };

    stage(0, 0);
    for (int t = 0; t < 8; ++t) {
        int p = t & 1;
        if (t + 1 < 8) { stage(p ^ 1, t + 1); VMCNT4; }
        else { VMCNT0; }
        __builtin_amdgcn_s_barrier();
        __builtin_amdgcn_sched_barrier(0);

        bf16x8 af[8], bf[4];
#pragma unroll
        for (int m = 0; m < 8; m++)
            af[m] = *(const bf16x8*)(As + p * 8192 + (wm * 8 + m) * 512 + lane * 8);
#pragma unroll
        for (int n = 0; n < 4; n++)
            bf[n] = *(const bf16x8*)(Bs + p * 8192 + (wn * 4 + n) * 512 + lane * 8);
#pragma unroll
        for (int m = 0; m < 8; m++)
#pragma unroll
            for (int n = 0; n < 4; n++)
                acc[m][n] = __builtin_amdgcn_mfma_f32_16x16x32_bf16(af[m], bf[n], acc[m][n], 0, 0, 0);

        __builtin_amdgcn_sched_barrier(0);
        __builtin_amdgcn_s_barrier();
    }

    float bn[4];
#pragma unroll
    for (int n = 0; n < 4; n++)
        bn[n] = bias[wn * 64 + n * 16 + rr];

    int erow = tid >> 3;
    int ec0  = (tid & 7) * 32;
#pragma unroll
    for (int pass = 0; pass < 4; ++pass) {
        __syncthreads();
        if (wm == (pass >> 1)) {
#pragma unroll
            for (int mm = 0; mm < 4; ++mm) {
                int m = (pass & 1) * 4 + mm;
#pragma unroll
                for (int n = 0; n < 4; ++n) {
                    int lcol = wn * 64 + n * 16 + rr;
#pragma unroll
                    for (int r = 0; r < 4; ++r)
                        ebuf[(mm * 16 + rbase + r) * ES + lcol] = acc[m][n][r] + bn[n];
                }
            }
        }
        __syncthreads();
        int grow = mBase + pass * 64 + erow;
        int v = inds[grow];
        const float* pr = res1 + (size_t)v * 256;
        f32x4 tv[8];
        float s = 0.f, s2 = 0.f;
#pragma unroll
        for (int g = 0; g < 8; ++g) {
            float4 e = *(float4*)(ebuf + erow * ES + ec0 + g * 4);
            float4 p = *(const float4*)(pr + ec0 + g * 4);
            f32x4 t = {e.x + p.x, e.y + p.y, e.z + p.z, e.w + p.w};
            tv[g] = t;
            s += t[0] + t[1] + t[2] + t[3];
            s2 += t[0]*t[0] + t[1]*t[1] + t[2]*t[2] + t[3]*t[3];
        }
#pragma unroll
        for (int off = 1; off < 8; off <<= 1) { s += __shfl_xor(s, off); s2 += __shfl_xor(s2, off); }
        float mean = s * (1.f/256.f);
        float var = fmaf(-mean, mean, s2 * (1.f/256.f));
        float rs = rsqrtf(var + 1e-5f);
        unsigned short* xb = out2 + (size_t)v * 256 + ec0;
#pragma unroll
        for (int g = 0; g < 4; ++g) {
            u16x8 o;
#pragma unroll
            for (int j = 0; j < 8; ++j) {
                int idx = g * 8 + j;
                float gg = g1[ec0 + idx];
                float bb = b1[ec0 + idx];
                o[j] = f2bf(fmaf((tv[idx >> 2][idx & 3] - mean) * rs, gg, bb));
            }
            *(u16x8*)(xb + g * 8) = o;
        }
    }
}

// ===================== fused FFN (FF1+FF2+LN2+LN3) =================
// R14 best-known: X (128x256 bf16 = 64KB) staged ONCE into fragment-order
// LDS; 128-slice main loop streams ONLY W via global_load_lds (counted
// vmcnt(2)); W stays L2-resident. Epilogue reads x as bf16 (from X).
__global__ __launch_bounds__(512, 2)
void ffn_fused(const unsigned short* __restrict__ X,   // [NVOX][256] bf16 (x_bf)
               const unsigned short* __restrict__ W1,  // [2048][256] bf16
               const unsigned short* __restrict__ W2,  // [256][2048] bf16
               const float* __restrict__ b1g,          // [2048]
               const float* __restrict__ b2g,          // [256]
               const float* __restrict__ prev,         // [NVOX][256] f32
               const float* __restrict__ lnG1, const float* __restrict__ lnB1,
               const float* __restrict__ lnG2, const float* __restrict__ lnB2,
               float* __restrict__ out) {
    __shared__ alignas(16) char smem[163840];
    unsigned short* Xs   = (unsigned short*)smem;               // 64 subtiles x 512 u16
    unsigned short* Wbuf = (unsigned short*)(smem + 65536);     // 2 x 8192 u16
    char*           HsB  = smem + 98304;                        // 128x256 u16 (swizzled)
    float*          ebuf = (float*)smem;                        // epilogue alias (16x264)
    const int ES = 264;

    int tid = threadIdx.x;
    int wave = tid >> 6, lane = tid & 63;
    int wm = wave >> 2;          // 0..1: rows wm*64..+64
    int wn = wave & 3;           // 0..3: cols wn*64..+64
    int mBase = blockIdx.x * 128;
    int rr = lane & 15;
    int kq = (lane >> 4) * 8;
    int rbase = (lane >> 4) * 4;

    auto gll = [&](const unsigned short* g, unsigned short* l) {
        __builtin_amdgcn_global_load_lds((const AS1 void*)g, (AS3 void*)l, 16, 0, 0);
    };

    // ---- prologue: stage ALL of X in fragment order ----
#pragma unroll
    for (int u = 0; u < 8; ++u)
        gll(X + (size_t)(mBase + wave * 16 + rr) * 256 + u * 32 + kq,
            Xs + (wave * 8 + u) * 512);

    auto stage_slice = [&](int s) {
        int c = s >> 4, half = (s >> 3) & 1, kt = s & 7;
        unsigned short* wb = Wbuf + (s & 1) * 8192;
        if (half == 0) {
            gll(W1 + (size_t)(c * 256 + (wave * 2 + 0) * 16 + rr) * 256 + kt * 32 + kq,
                wb + (wave * 2 + 0) * 512);
            gll(W1 + (size_t)(c * 256 + (wave * 2 + 1) * 16 + rr) * 256 + kt * 32 + kq,
                wb + (wave * 2 + 1) * 512);
        } else {
            gll(W2 + (size_t)((wave * 2 + 0) * 16 + rr) * 2048 + c * 256 + kt * 32 + kq,
                wb + (wave * 2 + 0) * 512);
            gll(W2 + (size_t)((wave * 2 + 1) * 16 + rr) * 2048 + c * 256 + kt * 32 + kq,
                wb + (wave * 2 + 1) * 512);
        }
    };

    f32x4 yacc[4][4];
    const f32x4 zero = {0.f, 0.f, 0.f, 0.f};
#pragma unroll
    for (int m = 0; m < 4; m++)
#pragma unroll
        for (int n = 0; n < 4; n++) yacc[m][n] = zero;

    stage_slice(0);
    __syncthreads();   // drains X staging + slice 0 (vmcnt 0)

    for (int c = 0; c < 8; ++c) {
        f32x4 hacc[4][4];
#pragma unroll
        for (int m = 0; m < 4; m++)
#pragma unroll
            for (int n = 0; n < 4; n++) hacc[m][n] = zero;

        // ---- FF1: 8 W1-slices; A from resident Xs ----
#pragma unroll
        for (int kt = 0; kt < 8; ++kt) {
            int s = c * 16 + kt;
            stage_slice(s + 1);
            VMCNT2;
            __builtin_amdgcn_s_barrier();
            __builtin_amdgcn_sched_barrier(0);

            bf16x8 af[4], bf[4];
#pragma unroll
            for (int m = 0; m < 4; m++)
                af[m] = *(const bf16x8*)(Xs + ((wm * 4 + m) * 8 + kt) * 512 + lane * 8);
#pragma unroll
            for (int n = 0; n < 4; n++)
                bf[n] = *(const bf16x8*)(Wbuf + (s & 1) * 8192 + (wn * 4 + n) * 512 + lane * 8);
#pragma unroll
            for (int m = 0; m < 4; m++)
#pragma unroll
                for (int n = 0; n < 4; n++)
                    hacc[m][n] = __builtin_amdgcn_mfma_f32_16x16x32_bf16(af[m], bf[n], hacc[m][n], 0, 0, 0);

            __builtin_amdgcn_sched_barrier(0);
            __builtin_amdgcn_s_barrier();
        }

        // ---- write Hc = relu(hacc + b1) to swizzled LDS ----
        {
            float b1v[4];
#pragma unroll
            for (int n = 0; n < 4; n++)
                b1v[n] = b1g[c * 256 + wn * 64 + n * 16 + rr];
#pragma unroll
            for (int m = 0; m < 4; m++)
#pragma unroll
                for (int n = 0; n < 4; n++)
#pragma unroll
                    for (int r = 0; r < 4; r++) {
                        float v = fmaxf(hacc[m][n][r] + b1v[n], 0.f);
                        int row = wm * 64 + m * 16 + rbase + r;
                        int col = wn * 64 + n * 16 + rr;
                        unsigned byte = (unsigned)(row * 512 + col * 2) ^ ((row & 7) << 4);
                        *(unsigned short*)(HsB + byte) = f2bf(v);
                    }
            LGKM0;
            __builtin_amdgcn_s_barrier();
        }

        // ---- FF2: 8 W2-slices over Hc, accumulate y ----
#pragma unroll
        for (int kt = 0; kt < 8; ++kt) {
            int s = c * 16 + 8 + kt;
            if (s + 1 < 128) { stage_slice(s + 1); VMCNT2; }
            else { VMCNT0; }
            __builtin_amdgcn_s_barrier();
            __builtin_amdgcn_sched_barrier(0);

            bf16x8 af[4], bf[4];
#pragma unroll
            for (int m = 0; m < 4; m++) {
                int row = wm * 64 + m * 16 + rr;
                unsigned byte = (unsigned)(row * 512 + kt * 64 + (lane >> 4) * 16) ^ ((rr & 7) << 4);
                af[m] = *(const bf16x8*)(HsB + byte);
            }
#pragma unroll
            for (int n = 0; n < 4; n++)
                bf[n] = *(const bf16x8*)(Wbuf + (s & 1) * 8192 + (wn * 4 + n) * 512 + lane * 8);
#pragma unroll
            for (int m = 0; m < 4; m++)
#pragma unroll
                for (int n = 0; n < 4; n++)
                    yacc[m][n] = __builtin_amdgcn_mfma_f32_16x16x32_bf16(af[m], bf[n], yacc[m][n], 0, 0, 0);

            __builtin_amdgcn_sched_barrier(0);
            __builtin_amdgcn_s_barrier();
        }
    }

    // ---- epilogue: out = LN( LN(y + b2 + x_bf) + prev ), 8 passes x 16 rows ----
    float b2v[4];
#pragma unroll
    for (int n = 0; n < 4; n++)
        b2v[n] = b2g[wn * 64 + n * 16 + rr];

    int erow = tid >> 5;              // 0..15
    int ec0  = (tid & 31) * 8;        // 0..248
#pragma unroll
    for (int p = 0; p < 8; ++p) {
        __syncthreads();
        if (wm == (p >> 2)) {
            const int m = p & 3;
#pragma unroll
            for (int n = 0; n < 4; ++n) {
                int lcol = wn * 64 + n * 16 + rr;
#pragma unroll
                for (int r = 0; r < 4; ++r)
                    ebuf[(rbase + r) * ES + lcol] = yacc[m][n][r] + b2v[n];
            }
        }
        __syncthreads();
        int grow = mBase + p * 16 + erow;

        float tv[8];
        float s1 = 0.f, s2 = 0.f;
        const unsigned short* xr = X + (size_t)grow * 256 + ec0;
        u16x8 xv = *(const u16x8*)xr;
#pragma unroll
        for (int j = 0; j < 8; ++j) {
            float t = ebuf[erow * ES + ec0 + j] + bf2f(xv[j]);
            tv[j] = t; s1 += t; s2 += t * t;
        }
#pragma unroll
        for (int off = 1; off < 32; off <<= 1) { s1 += __shfl_xor(s1, off); s2 += __shfl_xor(s2, off); }
        float mean = s1 * (1.f/256.f);
        float var = fmaf(-mean, mean, s2 * (1.f/256.f));
        float rs = rsqrtf(var + 1e-5f);

        const float* pr = prev + (size_t)grow * 256 + ec0;
        float s3 = 0.f, s4 = 0.f;
#pragma unroll
        for (int j = 0; j < 8; ++j) {
            float u = fmaf((tv[j] - mean) * rs, lnG1[ec0 + j], lnB1[ec0 + j]) + pr[j];
            tv[j] = u; s3 += u; s4 += u * u;
        }
#pragma unroll
        for (int off = 1; off < 32; off <<= 1) { s3 += __shfl_xor(s3, off); s4 += __shfl_xor(s4, off); }
        float mean2 = s3 * (1.f/256.f);
        float var2 = fmaf(-mean2, mean2, s4 * (1.f/256.f));
        float rs2 = rsqrtf(var2 + 1e-5f);

        float* od = out + (size_t)grow * 256 + ec0;
#pragma unroll
        for (int g = 0; g < 2; ++g) {
            float4 o;
            o.x = fmaf((tv[g*4+0] - mean2) * rs2, lnG2[ec0 + g*4+0], lnB2[ec0 + g*4+0]);
            o.y = fmaf((tv[g*4+1] - mean2) * rs2, lnG2[ec0 + g*4+1], lnB2[ec0 + g*4+1]);
            o.z = fmaf((tv[g*4+2] - mean2) * rs2, lnG2[ec0 + g*4+2], lnB2[ec0 + g*4+2]);
            o.w = fmaf((tv[g*4+3] - mean2) * rs2, lnG2[ec0 + g*4+3], lnB2[ec0 + g*4+3]);
            *(float4*)(od + g * 4) = o;
        }
    }
}

// ======================= MFMA attention ===========================
__global__ __launch_bounds__(256)
void attn_mfma_kernel(const unsigned short* __restrict__ QK,
                      const unsigned short* __restrict__ V,
                      const unsigned char* __restrict__ mask,
                      unsigned short* __restrict__ ao) {
    int s = blockIdx.x, h = blockIdx.y;
    int tid = threadIdx.x;
    int wq = tid >> 6;
    int lane = tid & 63;

    __shared__ alignas(16) unsigned short Ks[128 * 40];
    __shared__ alignas(16) unsigned short Vt[32 * 136];
    __shared__ alignas(16) unsigned short Plds[4 * 4096];
    __shared__ unsigned char msk[SSZ];

#pragma unroll
    for (int it = 0; it < 2; it++) {
        int idx = tid + it * 256;
        int key = idx >> 2, dimoff = (idx & 3) * 8;
        bf16x8 kv = *(const bf16x8*)(QK + (size_t)(s * SSZ + key) * 512 + 256 + h * HDIM + dimoff);
        *(bf16x8*)(Ks + key * 40 + dimoff) = kv;
        u16x8 vv = *(const u16x8*)(V + (size_t)(s * SSZ + key) * DM + h * HDIM + dimoff);
#pragma unroll
        for (int j = 0; j < 8; j++) Vt[(dimoff + j) * 136 + key] = vv[j];
    }
    if (tid < SSZ) msk[tid] = mask[s * SSZ + tid];
    __syncthreads();

    int rr = lane & 15;
    int kq = (lane >> 4) * 8;
    const f32x4 zero = {0.f, 0.f, 0.f, 0.f};

    bf16x8 qa[2];
#pragma unroll
    for (int mt = 0; mt < 2; mt++)
        qa[mt] = *(const bf16x8*)(QK + (size_t)(s * SSZ + wq * 32 + mt * 16 + rr) * 512 + h * HDIM + kq);

    f32x4 S[2][8];
    __builtin_amdgcn_s_setprio(1);
#pragma unroll
    for (int nt = 0; nt < 8; nt++) {
        bf16x8 kb = *(const bf16x8*)(Ks + (nt * 16 + rr) * 40 + kq);
#pragma unroll
        for (int mt = 0; mt < 2; mt++)
            S[mt][nt] = __builtin_amdgcn_mfma_f32_16x16x32_bf16(qa[mt], kb, zero, 0, 0, 0);
    }
    __builtin_amdgcn_s_setprio(0);

    const float SCALE = 0.17677669529663687f;
    f32x4 rm[2];
#pragma unroll
    for (int mt = 0; mt < 2; mt++) { rm[mt].x = rm[mt].y = rm[mt].z = rm[mt].w = -1e30f; }
#pragma unroll
    for (int nt = 0; nt < 8; nt++) {
        bool mv = msk[nt * 16 + rr] != 0;
#pragma unroll
        for (int mt = 0; mt < 2; mt++) {
#pragma unroll
            for (int r = 0; r < 4; r++) {
                float v = mv ? -1e30f : S[mt][nt][r] * SCALE;
                S[mt][nt][r] = v;
                rm[mt][r] = fmaxf(rm[mt][r], v);
            }
        }
    }
#pragma unroll
    for (int off = 1; off < 16; off <<= 1) {
#pragma unroll
        for (int mt = 0; mt < 2; mt++)
#pragma unroll
            for (int r = 0; r < 4; r++)
                rm[mt][r] = fmaxf(rm[mt][r], __shfl_xor(rm[mt][r], off));
    }

    f32x4 rs[2];
#pragma unroll
    for (int mt = 0; mt < 2; mt++) { rs[mt] = zero; }
#pragma unroll
    for (int nt = 0; nt < 8; nt++)
#pragma unroll
        for (int mt = 0; mt < 2; mt++)
#pragma unroll
            for (int r = 0; r < 4; r++) {
                float p = __expf(S[mt][nt][r] - rm[mt][r]);
                S[mt][nt][r] = p;
                rs[mt][r] += p;
            }
#pragma unroll
    for (int off = 1; off < 16; off <<= 1) {
#pragma unroll
        for (int mt = 0; mt < 2; mt++)
#pragma unroll
            for (int r = 0; r < 4; r++)
                rs[mt][r] += __shfl_xor(rs[mt][r], off);
    }

    char* Pbase = (char*)Plds + wq * 8192;
#pragma unroll
    for (int nt = 0; nt < 8; nt++)
#pragma unroll
        for (int mt = 0; mt < 2; mt++)
#pragma unroll
            for (int r = 0; r < 4; r++) {
                int prow = mt * 16 + (lane >> 4) * 4 + r;
                int col  = nt * 16 + rr;
                unsigned addr = (unsigned)(prow * 256 + col * 2) ^ ((prow & 7) << 4);
                *(unsigned short*)(Pbase + addr) = f2bf(S[mt][nt][r]);
            }
    __syncthreads();

    f32x4 O[2][2];
#pragma unroll
    for (int mt = 0; mt < 2; mt++)
#pragma unroll
        for (int nd = 0; nd < 2; nd++) O[mt][nd] = zero;
    __builtin_amdgcn_s_setprio(1);
#pragma unroll
    for (int kc = 0; kc < 4; kc++) {
        bf16x8 pa[2];
#pragma unroll
        for (int mt = 0; mt < 2; mt++) {
            int prow = mt * 16 + rr;
            unsigned addr = (unsigned)(prow * 256 + (kc * 32 + kq) * 2) ^ ((prow & 7) << 4);
            pa[mt] = *(const bf16x8*)(Pbase + addr);
        }
#pragma unroll
        for (int nd = 0; nd < 2; nd++) {
            bf16x8 vb = *(const bf16x8*)(Vt + (nd * 16 + rr) * 136 + kc * 32 + kq);
#pragma unroll
            for (int mt = 0; mt < 2; mt++)
                O[mt][nd] = __builtin_amdgcn_mfma_f32_16x16x32_bf16(pa[mt], vb, O[mt][nd], 0, 0, 0);
        }
    }
    __builtin_amdgcn_s_setprio(0);

#pragma unroll
    for (int mt = 0; mt < 2; mt++) {
#pragma unroll
        for (int nd = 0; nd < 2; nd++) {
#pragma unroll
            for (int r = 0; r < 4; r++) {
                int row = s * SSZ + wq * 32 + mt * 16 + (lane >> 4) * 4 + r;
                int col = h * HDIM + nd * 16 + rr;
                ao[(size_t)row * DM + col] = f2bf(O[mt][nd][r] / rs[mt][r]);
            }
        }
    }
}

// ============================= launch =============================
extern "C" void kernel_launch(void* const* d_in, const int* in_sizes, int n_in,
                              void* d_out, int out_size, void* d_ws, size_t ws_size,
                              hipStream_t stream) {
    const float* src       = (const float*)d_in[0];
    const float* pos_embed = (const float*)d_in[1];
    const int*   inds_all  = (const int*)d_in[2];
    const unsigned char* masks_all = (const unsigned char*)d_in[3];
    const float* w_qkv = (const float*)d_in[4];
    const float* b_qkv = (const float*)d_in[5];
    const float* w_out = (const float*)d_in[6];
    const float* b_out = (const float*)d_in[7];
    const float* w_ff1 = (const float*)d_in[8];
    const float* b_ff1 = (const float*)d_in[9];
    const float* w_ff2 = (const float*)d_in[10];
    const float* b_ff2 = (const float*)d_in[11];
    const float* g_n1 = (const float*)d_in[12];
    const float* b_n1 = (const float*)d_in[13];
    const float* g_n2 = (const float*)d_in[14];
    const float* b_n2 = (const float*)d_in[15];
    const float* g_ln = (const float*)d_in[16];
    const float* b_ln = (const float*)d_in[17];
    float* out = (float*)d_out;

    const size_t NVF = (size_t)NVOX * DM;  // 16,777,216
    unsigned short* A = (unsigned short*)d_ws;   // NVF u16: qk_bf -> ao_bf
    unsigned short* B = A + NVF;                 // NVF u16: feat_bf -> x_bf
    unsigned short* C = B + NVF;                 // 2*NVF u16: [Q|K]
    unsigned short* D = C + 2 * NVF;             // NVF u16: V bf16
    unsigned short* wts = D + NVF;
    const size_t SZ_QKV = (size_t)2 * 3 * DM * DM;
    const size_t SZ_WO  = (size_t)2 * DM * DM;
    const size_t SZ_FF1 = (size_t)2 * DFFN * DM;
    const size_t SZ_FF2 = (size_t)2 * DM * DFFN;
    unsigned short* wqkv_bf = wts;
    unsigned short* wo_bf   = wqkv_bf + SZ_QKV;
    unsigned short* wff1_bf = wo_bf + SZ_WO;
    unsigned short* wff2_bf = wff1_bf + SZ_FF1;

    cvt_all_kernel<<<1024, 256, 0, stream>>>(
        w_qkv, (int)SZ_QKV, w_out, (int)SZ_WO, w_ff1, (int)SZ_FF1, w_ff2, (int)SZ_FF2,
        wqkv_bf, wo_bf, wff1_bf, wff2_bf);

    for (int i = 0; i < 2; i++) {
        const float* prev = (i == 0) ? src : out;
        const int* inds = inds_all + (size_t)i * 2 * SNUM * SSZ;
        const unsigned char* mask = masks_all + (size_t)i * 2 * SNUM * SSZ;
        const float* pos  = pos_embed + (size_t)i * NVF;
        const unsigned short* wqkv = wqkv_bf + (size_t)i * 3 * DM * DM;
        const unsigned short* wo   = wo_bf + (size_t)i * DM * DM;
        const unsigned short* wff1 = wff1_bf + (size_t)i * DFFN * DM;
        const unsigned short* wff2 = wff2_bf + (size_t)i * DM * DFFN;
        const float* bqkv = b_qkv + (size_t)i * 3 * DM;
        const float* bo   = b_out + (size_t)i * DM;
        const float* bff1 = b_ff1 + (size_t)i * DFFN;
        const float* bff2 = b_ff2 + (size_t)i * DM;

        gather_kernel<<<NVOX / 4, 256, 0, stream>>>(prev, pos, inds, A, B);

        // [Q|K] -> C and V -> D in ONE dispatch (grid 256x3)
        qkv_mfma256<<<dim3(NVOX / 256, 3), 512, 0, stream>>>(
            A, B, wqkv, bqkv, C, D);

        attn_mfma_kernel<<<dim3(SNUM, NH), 256, 0, stream>>>(C, D, mask, A);

        // Wo GEMM + fused LN1 scatter: x[v]=LN(a+prev[v]) -> B (bf16 only)
        wo_mfma256<<<dim3(NVOX / 256), 512, 0, stream>>>(
            A, wo, bo, inds, prev, g_n1 + i * DM, b_n1 + i * DM, B);

        // fused FFN + LN2 + LN3 -> out (x read as bf16 from B)
        ffn_fused<<<dim3(NVOX / 128), 512, 0, stream>>>(
            B, wff1, wff2, bff1, bff2, prev,
            g_n2 + i * DM, b_n2 + i * DM, g_ln + i * DM, b_ln + i * DM, out);
    }
}